// Round 12
// baseline (10707.159 us; speedup 1.0000x reference)
//
#include <hip/hip_runtime.h>
#include <cstdint>

typedef __bf16 bf16x8 __attribute__((ext_vector_type(8)));
typedef float  f32x4  __attribute__((ext_vector_type(4)));

union U4B { uint4 u; bf16x8 b; };
__device__ __forceinline__ bf16x8 as_bf(uint4 u) { U4B x; x.u = u; return x.b; }

__device__ __forceinline__ unsigned short f2b(float x) {
  unsigned int u = __float_as_uint(x);
  unsigned int r = (u + 0x7fffu + ((u >> 16) & 1u)) >> 16;
  return (unsigned short)r;
}
__device__ __forceinline__ float b2f(unsigned int bits_lo16) {
  return __uint_as_float(bits_lo16 << 16);
}

__device__ __forceinline__ float sigm(float x) {
  float e = __builtin_amdgcn_exp2f(x * -1.4426950408889634f);
  return __builtin_amdgcn_rcpf(1.0f + e);
}
__device__ __forceinline__ float tanh_fast(float x) {
  float e = __builtin_amdgcn_exp2f(x * 2.8853900817779268f);
  return 1.0f - 2.0f * __builtin_amdgcn_rcpf(e + 1.0f);
}

// k-permutation: physical k' <-> original h-unit u (writer-contiguity layout).
// writer lane (kg,wid,m) writes physical k = kg*64 + wid*8 + m
// so original u = wid*32 + m*4 + kg = ((k>>3)&7)*32 + (k&7)*4 + (k>>6)
__device__ __forceinline__ int kperm_u(int k) {
  return ((k >> 3) & 7) * 32 + (k & 7) * 4 + (k >> 6);
}

// ---------------- prep: permuted bf16 weights in ws ----------------
__global__ void prep_kernel(const float* __restrict__ rec,
                            const float* __restrict__ kern,
                            const float* __restrict__ bias,
                            const float* __restrict__ dw,
                            unsigned short* __restrict__ recT,
                            unsigned short* __restrict__ kb2,
                            unsigned short* __restrict__ dwT) {
  int id = blockIdx.x * 256 + threadIdx.x;
  if (id < 262144) {                       // recT [1024 col'][256 k']
    int colp = id >> 8, k = id & 255;
    int u = kperm_u(k);
    int oc = (colp >> 2) + 256 * (colp & 3);
    recT[colp * 256 + k] = f2b(rec[u * 1024 + oc]);
  } else if (id < 262144 + 131072) {       // kb2 [128 ch][1024 col']
    int i = id - 262144;
    int ch = i >> 10, colp = i & 1023;
    int oc = (colp >> 2) + 256 * (colp & 3);
    kb2[ch * 1024 + colp] = f2b(kern[ch * 1024 + oc] + bias[oc]);
  } else {                                 // dwT [128 class][256 k']
    int i = id - 262144 - 131072;
    int cls = i >> 8, k = i & 255;
    int u = kperm_u(k);
    dwT[cls * 256 + k] = f2b(dw[u * 128 + cls]);
  }
}

// ---------------- DIAGNOSTIC: pure step skeleton, 16384 steps ----------------
// Per step: 8 swizzled ds_read_b128 -> dependent xor -> packed ds_write_b128
// -> __syncthreads. No MFMA, no trans, no VMEM. Same grid/waves/LDS-h layout
// as the real kernel. skel_per_step = dur/16384 decomposes structure vs content.
#define SKEL_STEPS 16384
__global__ __launch_bounds__(512)
__attribute__((amdgpu_waves_per_eu(2, 2)))
void skel_kernel(uint4* __restrict__ sink) {
  __shared__ unsigned short h_buf[2][16][288];
  const int tid   = threadIdx.x;
  const int lane  = tid & 63;
  const int wid   = tid >> 6;
  const int row16 = lane & 15;
  const int kg    = lane >> 4;

  for (int e = tid; e < 2 * 16 * 288 / 8; e += 512)
    ((uint4*)h_buf)[e] = uint4{0, 0, 0, 0};

  char* lds = (char*)&h_buf[0][0][0];
  const unsigned swz   = (unsigned)((row16 & 7) << 4);
  const unsigned rowB  = (unsigned)(row16 * 576);
  const unsigned kgo   = (unsigned)(kg * 16);
  const unsigned wrOff = rowB + (((unsigned)(kg * 128 + wid * 16)) ^ swz);

  __syncthreads();
  uint4 acc = {0u, 0u, 0u, 0u};
  int cur = 0;
#pragma unroll 1
  for (int t = 0; t < SKEL_STEPS; ++t) {
    const char* hrdRow = lds + cur * 9216 + rowB;
#pragma unroll
    for (int k = 0; k < 8; ++k) {
      uint4 hf = *(const uint4*)(hrdRow + ((((unsigned)(k * 64)) + kgo) ^ swz));
      acc.x ^= hf.x; acc.y ^= hf.y; acc.z ^= hf.z; acc.w ^= hf.w;
    }
    *(uint4*)(lds + (cur ^ 1) * 9216 + wrOff) = acc;
    __syncthreads();
    cur ^= 1;
  }
  sink[blockIdx.x * 512 + tid] = acc;
}

// ---------------- real kernel: R9 tiering + R11 swizzle + packed write ----------------
// 64 blocks x 512 threads (8 waves, 2/SIMD, 256-reg unified budget).
// Wave wid owns 8 m-tiles: m0..3 AGPR (128 accum, R9-proven spill-free),
// m4..5 LDS (128 KB), m6..7 streamed (burst-hi at step start, reissue-lo in
// group B). h in LDS swizzled both-sides (R11-verified); single packed b128
// h-write per lane (kperm layout baked into recT/dwT k-axes).
__global__ __launch_bounds__(512)
__attribute__((amdgpu_waves_per_eu(2, 2)))
void lstm_kernel(
    const unsigned short* __restrict__ recT,
    const unsigned short* __restrict__ kb2,
    const unsigned short* __restrict__ dwT,
    const int* __restrict__ x,
    const float* __restrict__ dense_b,
    float* __restrict__ out) {
  __shared__ uint4 A_lds[2][8][512];            // 128 KB (m4,m5)
  __shared__ unsigned short h_buf[2][16][288];  // 18 KB swizzled
  __shared__ float l_lds[16][132];              // 8.4 KB

  const int tid   = threadIdx.x;
  const int lane  = tid & 63;
  const int wid   = tid >> 6;
  const int row16 = lane & 15;
  const int kg    = lane >> 4;
  const int rbase = blockIdx.x << 4;

  const unsigned short* recBase = recT + ((wid * 128 + row16) * 256 + kg * 8);

  // m0..3 -> AGPRs (128 accum regs; exactly R9's proven footprint)
  uint4 af[4][8];
#pragma unroll
  for (int m = 0; m < 4; ++m)
#pragma unroll
    for (int k = 0; k < 8; ++k) {
      af[m][k] = *(const uint4*)(recBase + m * 4096 + k * 32);
      asm volatile("" : "+a"(af[m][k].x), "+a"(af[m][k].y),
                        "+a"(af[m][k].z), "+a"(af[m][k].w));
    }

  // m4..5 -> LDS, staged once
#pragma unroll
  for (int s = 0; s < 2; ++s)
#pragma unroll
    for (int k = 0; k < 8; ++k)
      A_lds[s][k][wid * 64 + lane] = *(const uint4*)(recBase + (4 + s) * 4096 + k * 32);

  // m6..7 stream bases; preload lo frags 0..3
  const unsigned short* sb6 = recBase + 6 * 4096;
  const unsigned short* sb7 = recBase + 7 * 4096;
  uint4 st6[8], st7[8];
#pragma unroll
  for (int k = 0; k < 4; ++k) {
    st6[k] = *(const uint4*)(sb6 + k * 32);
    st7[k] = *(const uint4*)(sb7 + k * 32);
  }

  for (int e = tid; e < 2 * 16 * 288 / 8; e += 512)
    ((uint4*)h_buf)[e] = uint4{0, 0, 0, 0};

  float c_state[8];
#pragma unroll
  for (int m = 0; m < 8; ++m) c_state[m] = 0.0f;

  const int* xrow = x + (rbase + row16) * 512;
  int idx = xrow[0];

  char* lds = (char*)&h_buf[0][0][0];
  const unsigned swz   = (unsigned)((row16 & 7) << 4);
  const unsigned rowB  = (unsigned)(row16 * 576);
  const unsigned kgo   = (unsigned)(kg * 16);
  const unsigned wrOff = rowB + (((unsigned)(kg * 128 + wid * 16)) ^ swz);
  const unsigned aoff_base = (wid * 64 + lane) * 16;

  __syncthreads();

  int cur = 0;
#pragma unroll 1
  for (int t = 0; t < 512; ++t) {
    unsigned z6 = 0, zL = 0;
    asm volatile("" : "+v"(z6), "+v"(zL));
    const unsigned short* sb6v = sb6 + z6;
    const unsigned short* sb7v = sb7 + z6;
    const unsigned aoff = aoff_base + zL;

    // kq for this step (consumed at gates, >=1000 cyc away)
    const unsigned short* kb = kb2 + (idx * 1024 + wid * 128 + kg * 4);
    uint2 kq[8];
#pragma unroll
    for (int m = 0; m < 8; ++m) kq[m] = *(const uint2*)(kb + m * 16);
    int idx_next = xrow[(t + 1 < 512) ? t + 1 : 511];

    // burst: hi stream frags for THIS step (consumed in group B)
#pragma unroll
    for (int k = 4; k < 8; ++k) {
      st6[k] = *(const uint4*)(sb6v + k * 32);
      st7[k] = *(const uint4*)(sb7v + k * 32);
    }

    const char* hrdRow = lds + cur * 9216 + rowB;
    unsigned short hb[8];

    // ---- group A: m0..3 from AGPRs ----
    {
      f32x4 a0 = {0,0,0,0}, a1 = {0,0,0,0}, a2 = {0,0,0,0}, a3 = {0,0,0,0};
#pragma unroll
      for (int k = 0; k < 8; ++k) {
        uint4 hf = *(const uint4*)(hrdRow + ((((unsigned)(k * 64)) + kgo) ^ swz));
        a0 = __builtin_amdgcn_mfma_f32_16x16x32_bf16(as_bf(af[0][k]), as_bf(hf), a0, 0, 0, 0);
        a1 = __builtin_amdgcn_mfma_f32_16x16x32_bf16(as_bf(af[1][k]), as_bf(hf), a1, 0, 0, 0);
        a2 = __builtin_amdgcn_mfma_f32_16x16x32_bf16(as_bf(af[2][k]), as_bf(hf), a2, 0, 0, 0);
        a3 = __builtin_amdgcn_mfma_f32_16x16x32_bf16(as_bf(af[3][k]), as_bf(hf), a3, 0, 0, 0);
      }
      f32x4 ag[4] = {a0, a1, a2, a3};
#pragma unroll
      for (int m = 0; m < 4; ++m) {
        float zi = ag[m][0] + b2f(kq[m].x & 0xffffu);
        float zf = ag[m][1] + b2f(kq[m].x >> 16);
        float zg = ag[m][2] + b2f(kq[m].y & 0xffffu);
        float zo = ag[m][3] + b2f(kq[m].y >> 16);
        float c  = sigm(zf) * c_state[m] + sigm(zi) * tanh_fast(zg);
        c_state[m] = c;
        hb[m] = f2b(sigm(zo) * tanh_fast(c));
      }
    }

    // ---- group B: m4..5 (LDS) + m6..7 (streamed) ----
    {
      f32x4 b0 = {0,0,0,0}, b1 = {0,0,0,0}, b2v = {0,0,0,0}, b3 = {0,0,0,0};
#pragma unroll
      for (int k = 0; k < 8; ++k) {
        uint4 hf = *(const uint4*)(hrdRow + ((((unsigned)(k * 64)) + kgo) ^ swz));
        uint4 a4 = *(const uint4*)((const char*)A_lds + (0 * 8 + k) * 8192 + aoff);
        uint4 a5 = *(const uint4*)((const char*)A_lds + (1 * 8 + k) * 8192 + aoff);
        b0  = __builtin_amdgcn_mfma_f32_16x16x32_bf16(as_bf(a4), as_bf(hf), b0, 0, 0, 0);
        b1  = __builtin_amdgcn_mfma_f32_16x16x32_bf16(as_bf(a5), as_bf(hf), b1, 0, 0, 0);
        b2v = __builtin_amdgcn_mfma_f32_16x16x32_bf16(as_bf(st6[k]), as_bf(hf), b2v, 0, 0, 0);
        b3  = __builtin_amdgcn_mfma_f32_16x16x32_bf16(as_bf(st7[k]), as_bf(hf), b3, 0, 0, 0);
        if (k < 4) {  // reissue lo frag for t+1 (full-step prefetch distance)
          st6[k] = *(const uint4*)(sb6v + k * 32);
          st7[k] = *(const uint4*)(sb7v + k * 32);
        }
      }
      f32x4 bg[4] = {b0, b1, b2v, b3};
#pragma unroll
      for (int m = 0; m < 4; ++m) {
        float zi = bg[m][0] + b2f(kq[4 + m].x & 0xffffu);
        float zf = bg[m][1] + b2f(kq[4 + m].x >> 16);
        float zg = bg[m][2] + b2f(kq[4 + m].y & 0xffffu);
        float zo = bg[m][3] + b2f(kq[4 + m].y >> 16);
        float c  = sigm(zf) * c_state[4 + m] + sigm(zi) * tanh_fast(zg);
        c_state[4 + m] = c;
        hb[4 + m] = f2b(sigm(zo) * tanh_fast(c));
      }
    }

    // packed single b128 h-write (kperm layout)
    uint4 hwv;
    hwv.x = (unsigned)hb[0] | ((unsigned)hb[1] << 16);
    hwv.y = (unsigned)hb[2] | ((unsigned)hb[3] << 16);
    hwv.z = (unsigned)hb[4] | ((unsigned)hb[5] << 16);
    hwv.w = (unsigned)hb[6] | ((unsigned)hb[7] << 16);
    *(uint4*)(lds + (cur ^ 1) * 9216 + wrOff) = hwv;

    __syncthreads();
    cur ^= 1;
    idx = idx_next;
  }

  // ---- final dense (MFMA) + softmax; final h in buffer 0 ----
  {
    const unsigned short* dwBase = dwT + ((wid * 16 + row16) * 256 + kg * 8);
    f32x4 la = {0.f, 0.f, 0.f, 0.f};
#pragma unroll
    for (int k = 0; k < 8; ++k) {
      uint4 hf  = *(const uint4*)(lds + rowB + ((((unsigned)(k * 64)) + kgo) ^ swz));
      uint4 afd = *(const uint4*)(dwBase + k * 32);
      la = __builtin_amdgcn_mfma_f32_16x16x32_bf16(as_bf(afd), as_bf(hf), la, 0, 0, 0);
    }
#pragma unroll
    for (int r = 0; r < 4; ++r) {
      int cls = wid * 16 + kg * 4 + r;
      l_lds[row16][cls] = la[r] + dense_b[cls];
    }
  }
  __syncthreads();

  {
    int r = tid >> 5, cg = tid & 31;
    float4 v = *(const float4*)&l_lds[r][cg * 4];
    float mx = fmaxf(fmaxf(v.x, v.y), fmaxf(v.z, v.w));
#pragma unroll
    for (int sh = 1; sh < 32; sh <<= 1) mx = fmaxf(mx, __shfl_xor(mx, sh));
    const float L2E = 1.4426950408889634f;
    float e0 = __builtin_amdgcn_exp2f((v.x - mx) * L2E);
    float e1 = __builtin_amdgcn_exp2f((v.y - mx) * L2E);
    float e2 = __builtin_amdgcn_exp2f((v.z - mx) * L2E);
    float e3 = __builtin_amdgcn_exp2f((v.w - mx) * L2E);
    float sm = e0 + e1 + e2 + e3;
#pragma unroll
    for (int sh = 1; sh < 32; sh <<= 1) sm += __shfl_xor(sm, sh);
    float inv = __builtin_amdgcn_rcpf(sm);
    float4 o = {e0 * inv, e1 * inv, e2 * inv, e3 * inv};
    *(float4*)&out[(rbase + r) * 128 + cg * 4] = o;
  }
}

extern "C" void kernel_launch(void* const* d_in, const int* in_sizes, int n_in,
                              void* d_out, int out_size, void* d_ws, size_t ws_size,
                              hipStream_t stream) {
  const int*   x      = (const int*)d_in[0];    // [1024][512] int32
  const float* kern   = (const float*)d_in[1];  // [128][1024]
  const float* rec    = (const float*)d_in[2];  // [256][1024]
  const float* bias   = (const float*)d_in[3];  // [1024]
  const float* dw     = (const float*)d_in[4];  // [256][128]
  const float* db     = (const float*)d_in[5];  // [128]
  float* outp = (float*)d_out;                  // [1024][128]

  unsigned char* ws = (unsigned char*)d_ws;
  unsigned short* recT = (unsigned short*)(ws);            // 512 KB
  unsigned short* kb2  = (unsigned short*)(ws + 524288);   // 256 KB
  unsigned short* dwT  = (unsigned short*)(ws + 786432);   //  64 KB
  uint4*          sink = (uint4*)(ws + 851968);            // 512 KB diag sink

  prep_kernel<<<1664, 256, 0, stream>>>(rec, kern, bias, dw, recT, kb2, dwT);
  skel_kernel<<<64, 512, 0, stream>>>(sink);
  lstm_kernel<<<64, 512, 0, stream>>>(recT, kb2, dwT, x, db, outp);
}